// Round 1
// baseline (572.754 us; speedup 1.0000x reference)
//
#include <hip/hip_runtime.h>
#include <hip/hip_bf16.h>
#include <stdint.h>

typedef unsigned short ushort_t;
typedef __bf16 bf16x8 __attribute__((ext_vector_type(8)));
typedef float f32x4 __attribute__((ext_vector_type(4)));

// ---------- helpers ----------
__device__ __forceinline__ ushort_t f2bf(float f) {
    union { float f; unsigned u; } v; v.f = f;
    unsigned u = v.u;
    unsigned r = u + 0x7fffu + ((u >> 16) & 1u);   // RNE
    return (ushort_t)(r >> 16);
}
__device__ __forceinline__ float bf2f(ushort_t h) {
    union { unsigned u; float f; } v; v.u = ((unsigned)h) << 16;
    return v.f;
}

#define GLDS16(gsrc, ldst)                                                    \
    __builtin_amdgcn_global_load_lds(                                         \
        (const __attribute__((address_space(1))) void*)(gsrc),                \
        (__attribute__((address_space(3))) void*)(ldst), 16, 0, 0)

// ---------- kernel 1: weight convert + accumulator zero ----------
__global__ __launch_bounds__(256) void prep_kernel(
    const float* __restrict__ W1, const float* __restrict__ W2,
    ushort_t* __restrict__ W1p, ushort_t* __restrict__ W2b,
    float* __restrict__ stats)
{
    int idx = blockIdx.x * 256 + threadIdx.x;
    if (idx < 512 * 800) {
        int n = idx / 800, k = idx - n * 800;
        W1p[idx] = (k < 784) ? f2bf(W1[n * 784 + k]) : (ushort_t)0;
    }
    if (idx < 128 * 512) W2b[idx] = f2bf(W2[idx]);
    if (idx == 0) stats[0] = 0.0f;
}

// ---------- kernel 2: h1 = relu(X_all @ W1p^T + b1), bf16 out ----------
// M = 69632 (= 544*128: rows 0..65535 from x, rest from x_unlab), N=512, Kp=800
__global__ __launch_bounds__(256) void gemm1_kernel(
    const float* __restrict__ x, const float* __restrict__ xu,
    const ushort_t* __restrict__ W1p, const float* __restrict__ b1,
    ushort_t* __restrict__ h1)
{
    __shared__ ushort_t As[128 * 32];
    __shared__ ushort_t Bs[128 * 32];

    const int tile_n = blockIdx.x & 3;
    const int tile_m = blockIdx.x >> 2;
    const int tid = threadIdx.x;
    const int w = tid >> 6, lane = tid & 63;
    const int wm = w >> 1, wn = w & 1;
    const int quad = lane >> 4, lc = lane & 15;

    // A staging: thread -> row tid/2, 16-float chunk (tid&1)
    const int arow = tid >> 1;
    const int akoff = (tid & 1) * 16;
    const int grow = tile_m * 128 + arow;
    const float* asrc = (grow < 65536) ? (x + (size_t)grow * 784)
                                       : (xu + (size_t)(grow - 65536) * 784);
    // B staging (async): per wave 2 chunks of 1KB
    const int brow_in = (lane >> 2);
    const int bkoff = (lane & 3) * 8;

    f32x4 acc[4][4];
#pragma unroll
    for (int i = 0; i < 4; i++)
#pragma unroll
        for (int j = 0; j < 4; j++)
#pragma unroll
            for (int r = 0; r < 4; r++) acc[i][j][r] = 0.0f;

    for (int k0 = 0; k0 < 800; k0 += 32) {
        // async B tile loads (wave-uniform LDS base; dest = base + lane*16)
#pragma unroll
        for (int c = 0; c < 2; c++) {
            int row = (w * 2 + c) * 16 + brow_in;
            const ushort_t* src =
                W1p + (size_t)(tile_n * 128 + row) * 800 + k0 + bkoff;
            GLDS16(src, Bs + (w * 2 + c) * 512);
        }
        // manual A stage: fp32 load -> bf16 -> LDS
        {
            int kch = k0 + akoff;
            uint4 lo, hi;
            if (kch < 784) {
                const float4* p = (const float4*)(asrc + kch);
                float4 f0 = p[0], f1 = p[1], f2 = p[2], f3 = p[3];
                lo.x = ((unsigned)f2bf(f0.y) << 16) | f2bf(f0.x);
                lo.y = ((unsigned)f2bf(f0.w) << 16) | f2bf(f0.z);
                lo.z = ((unsigned)f2bf(f1.y) << 16) | f2bf(f1.x);
                lo.w = ((unsigned)f2bf(f1.w) << 16) | f2bf(f1.z);
                hi.x = ((unsigned)f2bf(f2.y) << 16) | f2bf(f2.x);
                hi.y = ((unsigned)f2bf(f2.w) << 16) | f2bf(f2.z);
                hi.z = ((unsigned)f2bf(f3.y) << 16) | f2bf(f3.x);
                hi.w = ((unsigned)f2bf(f3.w) << 16) | f2bf(f3.z);
            } else {
                lo = make_uint4(0, 0, 0, 0);
                hi = make_uint4(0, 0, 0, 0);
            }
            *(uint4*)&As[arow * 32 + akoff] = lo;
            *(uint4*)&As[arow * 32 + akoff + 8] = hi;
        }
        __syncthreads();

        bf16x8 af[4], bfr[4];
#pragma unroll
        for (int i = 0; i < 4; i++)
            af[i] = *(const bf16x8*)&As[(wm * 64 + i * 16 + lc) * 32 + quad * 8];
#pragma unroll
        for (int j = 0; j < 4; j++)
            bfr[j] = *(const bf16x8*)&Bs[(wn * 64 + j * 16 + lc) * 32 + quad * 8];
#pragma unroll
        for (int i = 0; i < 4; i++)
#pragma unroll
            for (int j = 0; j < 4; j++)
                acc[i][j] = __builtin_amdgcn_mfma_f32_16x16x32_bf16(
                    af[i], bfr[j], acc[i][j], 0, 0, 0);
        __syncthreads();
    }

    // epilogue: relu(acc + b1) -> bf16
    float bias[4];
#pragma unroll
    for (int j = 0; j < 4; j++)
        bias[j] = b1[tile_n * 128 + wn * 64 + j * 16 + lc];
#pragma unroll
    for (int i = 0; i < 4; i++) {
        int gr0 = tile_m * 128 + wm * 64 + i * 16 + quad * 4;
#pragma unroll
        for (int j = 0; j < 4; j++) {
            int gc = tile_n * 128 + wn * 64 + j * 16 + lc;
#pragma unroll
            for (int r = 0; r < 4; r++) {
                float v = acc[i][j][r] + bias[j];
                v = fmaxf(v, 0.0f);
                h1[(size_t)(gr0 + r) * 512 + gc] = f2bf(v);
            }
        }
    }
}

// ---------- kernel 3: h2 = relu(h1 @ W2b^T + b2), bf16 out ----------
// M = 69632, N = 128, K = 512
__global__ __launch_bounds__(256) void gemm2_kernel(
    const ushort_t* __restrict__ h1, const ushort_t* __restrict__ W2b,
    const float* __restrict__ b2, ushort_t* __restrict__ h2)
{
    __shared__ ushort_t As[128 * 32];
    __shared__ ushort_t Bs[128 * 32];

    const int tile_m = blockIdx.x;
    const int tid = threadIdx.x;
    const int w = tid >> 6, lane = tid & 63;
    const int wm = w >> 1, wn = w & 1;
    const int quad = lane >> 4, lc = lane & 15;
    const int row_in = (lane >> 2);
    const int koff = (lane & 3) * 8;

    f32x4 acc[4][4];
#pragma unroll
    for (int i = 0; i < 4; i++)
#pragma unroll
        for (int j = 0; j < 4; j++)
#pragma unroll
            for (int r = 0; r < 4; r++) acc[i][j][r] = 0.0f;

    for (int k0 = 0; k0 < 512; k0 += 32) {
#pragma unroll
        for (int c = 0; c < 2; c++) {
            int row = (w * 2 + c) * 16 + row_in;
            const ushort_t* srcA =
                h1 + (size_t)(tile_m * 128 + row) * 512 + k0 + koff;
            GLDS16(srcA, As + (w * 2 + c) * 512);
            const ushort_t* srcB = W2b + (size_t)row * 512 + k0 + koff;
            GLDS16(srcB, Bs + (w * 2 + c) * 512);
        }
        __syncthreads();

        bf16x8 af[4], bfr[4];
#pragma unroll
        for (int i = 0; i < 4; i++)
            af[i] = *(const bf16x8*)&As[(wm * 64 + i * 16 + lc) * 32 + quad * 8];
#pragma unroll
        for (int j = 0; j < 4; j++)
            bfr[j] = *(const bf16x8*)&Bs[(wn * 64 + j * 16 + lc) * 32 + quad * 8];
#pragma unroll
        for (int i = 0; i < 4; i++)
#pragma unroll
            for (int j = 0; j < 4; j++)
                acc[i][j] = __builtin_amdgcn_mfma_f32_16x16x32_bf16(
                    af[i], bfr[j], acc[i][j], 0, 0, 0);
        __syncthreads();
    }

    float bias[4];
#pragma unroll
    for (int j = 0; j < 4; j++) bias[j] = b2[wn * 64 + j * 16 + lc];
#pragma unroll
    for (int i = 0; i < 4; i++) {
        int gr0 = tile_m * 128 + wm * 64 + i * 16 + quad * 4;
#pragma unroll
        for (int j = 0; j < 4; j++) {
            int gc = wn * 64 + j * 16 + lc;
#pragma unroll
            for (int r = 0; r < 4; r++) {
                float v = acc[i][j][r] + bias[j];
                v = fmaxf(v, 0.0f);
                h2[(size_t)(gr0 + r) * 128 + gc] = f2bf(v);
            }
        }
    }
}

// ---------- kernel 4: fused fc3 + BCE partial / unlabeled logits ----------
// 64 rows per block; grid = 69632/64 = 1088
__global__ __launch_bounds__(256) void loss_kernel(
    const ushort_t* __restrict__ h2, const int* __restrict__ y,
    const float* __restrict__ W3, const float* __restrict__ b3,
    float* __restrict__ stats, float* __restrict__ logits_u)
{
    __shared__ float W3s[10 * 128];
    __shared__ float b3s[10];
    __shared__ ushort_t h2s[64 * 128];
    __shared__ float red[4];

    const int tid = threadIdx.x;
    for (int i = tid; i < 1280; i += 256) W3s[i] = W3[i];
    if (tid < 10) b3s[tid] = b3[tid];

    const size_t row0 = (size_t)blockIdx.x * 64;
    const ushort_t* src = h2 + row0 * 128;
#pragma unroll
    for (int i = tid * 8; i < 64 * 128; i += 256 * 8)
        *(uint4*)&h2s[i] = *(const uint4*)&src[i];
    __syncthreads();

    float bce_part = 0.0f;
    for (int o = tid; o < 640; o += 256) {
        int r = o / 10, c = o - r * 10;
        size_t grow = row0 + r;
        float acc = b3s[c];
        const ushort_t* hr = &h2s[r * 128];
        const float* wr = &W3s[c * 128];
#pragma unroll 8
        for (int k = 0; k < 128; k++) acc += bf2f(hr[k]) * wr[k];
        if (grow < 65536) {
            float t = (y[grow] == c) ? 1.0f : 0.0f;
            bce_part += fmaxf(acc, 0.0f) - acc * t +
                        log1pf(__expf(-fabsf(acc)));
        } else {
            logits_u[(grow - 65536) * 10 + c] = acc;
        }
    }
    // block reduction
#pragma unroll
    for (int s = 32; s > 0; s >>= 1) bce_part += __shfl_down(bce_part, s, 64);
    if ((tid & 63) == 0) red[tid >> 6] = bce_part;
    __syncthreads();
    if (tid == 0) {
        float v = red[0] + red[1] + red[2] + red[3];
        atomicAdd(stats, v);
    }
}

// ---------- kernel 5: semantic-loss finisher + output write ----------
// log_s[c] = S[c] + logsumexp_i(o_i[c]),  S[c] = sum_i logsigmoid(-o_i[c])
__global__ __launch_bounds__(512) void finisher_kernel(
    const float* __restrict__ logits_u, const float* __restrict__ stats,
    float* __restrict__ out)
{
    __shared__ float Rs[32][16];
    __shared__ float Rm[32][16];
    __shared__ float Scol[16], Mcol[16];

    const int tid = threadIdx.x;
    const int c = tid & 15, g = tid >> 4;   // 32 groups x 16 cols
    float s = 0.0f, m = -1e30f;
    if (c < 10) {
        for (int i = g; i < 4096; i += 32) {
            float o = logits_u[i * 10 + c];
            s += fminf(-o, 0.0f) - log1pf(__expf(-fabsf(o)));
            m = fmaxf(m, o);
        }
    }
    Rs[g][c] = s;
    Rm[g][c] = m;
    __syncthreads();
    if (tid < 16) {
        float ss = 0.0f, mm = -1e30f;
        for (int gg = 0; gg < 32; gg++) {
            ss += Rs[gg][tid];
            mm = fmaxf(mm, Rm[gg][tid]);
        }
        Scol[tid] = ss;
        Mcol[tid] = mm;
    }
    __syncthreads();
    float e = 0.0f;
    if (c < 10) {
        float mm = Mcol[c];
        for (int i = g; i < 4096; i += 32)
            e += __expf(logits_u[i * 10 + c] - mm);
    }
    Rs[g][c] = e;
    __syncthreads();
    if (tid == 0) {
        float sl = 0.0f;
        for (int cc = 0; cc < 10; cc++) {
            float ee = 0.0f;
            for (int gg = 0; gg < 32; gg++) ee += Rs[gg][cc];
            sl += -(Scol[cc] + Mcol[cc] + __logf(ee));
        }
        sl *= 0.1f;
        out[0] = stats[0] * (1.0f / (65536.0f * 10.0f));
        out[1] = sl;
    }
}

// ---------- launch ----------
extern "C" void kernel_launch(void* const* d_in, const int* in_sizes, int n_in,
                              void* d_out, int out_size, void* d_ws,
                              size_t ws_size, hipStream_t stream)
{
    const float* x  = (const float*)d_in[0];   // 65536x784
    const int*   y  = (const int*)d_in[1];     // 65536
    const float* xu = (const float*)d_in[2];   // 4096x784
    const float* W1 = (const float*)d_in[3];   // 512x784
    const float* b1 = (const float*)d_in[4];   // 512
    const float* W2 = (const float*)d_in[5];   // 128x512
    const float* b2 = (const float*)d_in[6];   // 128
    const float* W3 = (const float*)d_in[7];   // 10x128
    const float* b3 = (const float*)d_in[8];   // 10
    float* out = (float*)d_out;

    char* ws = (char*)d_ws;
    // ws layout (bytes), ~90.3 MB total
    ushort_t* W1p      = (ushort_t*)(ws + 0);         // 512*800*2   = 819200
    ushort_t* W2b      = (ushort_t*)(ws + 819200);    // 128*512*2   = 131072
    float*    stats    = (float*)(ws + 950272);       // 4 B (+pad)
    float*    logits_u = (float*)(ws + 950528);       // 4096*10*4   = 163840
    ushort_t* h1       = (ushort_t*)(ws + 1114368);   // 69632*512*2 = 71303168
    ushort_t* h2       = (ushort_t*)(ws + 72417536);  // 69632*128*2 = 17825792

    prep_kernel<<<1600, 256, 0, stream>>>(W1, W2, W1p, W2b, stats);
    gemm1_kernel<<<544 * 4, 256, 0, stream>>>(x, xu, W1p, b1, h1);
    gemm2_kernel<<<544, 256, 0, stream>>>(h1, W2b, b2, h2);
    loss_kernel<<<1088, 256, 0, stream>>>(h2, y, W3, b3, stats, logits_u);
    finisher_kernel<<<1, 512, 0, stream>>>(logits_u, stats, out);
    (void)in_sizes; (void)n_in; (void)out_size; (void)ws_size;
}

// Round 2
// 552.899 us; speedup vs baseline: 1.0359x; 1.0359x over previous
//
#include <hip/hip_runtime.h>
#include <hip/hip_bf16.h>
#include <stdint.h>

typedef unsigned short ushort_t;
typedef __bf16 bf16x8 __attribute__((ext_vector_type(8)));
typedef float f32x4 __attribute__((ext_vector_type(4)));

// ---------- helpers ----------
__device__ __forceinline__ ushort_t f2bf(float f) {
    union { float f; unsigned u; } v; v.f = f;
    unsigned u = v.u;
    unsigned r = u + 0x7fffu + ((u >> 16) & 1u);   // RNE
    return (ushort_t)(r >> 16);
}
__device__ __forceinline__ float bf2f(ushort_t h) {
    union { unsigned u; float f; } v; v.u = ((unsigned)h) << 16;
    return v.f;
}

#define GLDS16(gsrc, ldst)                                                    \
    __builtin_amdgcn_global_load_lds(                                         \
        (const __attribute__((address_space(1))) void*)(gsrc),                \
        (__attribute__((address_space(3))) void*)(ldst), 16, 0, 0)

// ---------- prep: W1 -> padded bf16, W2 -> bf16, stats=0 ----------
__global__ __launch_bounds__(256) void prep_kernel(
    const float* __restrict__ W1, const float* __restrict__ W2,
    ushort_t* __restrict__ W1p, ushort_t* __restrict__ W2b,
    float* __restrict__ stats)
{
    int idx = blockIdx.x * 256 + threadIdx.x;
    if (idx < 512 * 800) {
        int n = idx / 800, k = idx - n * 800;
        W1p[idx] = (k < 784) ? f2bf(W1[n * 784 + k]) : (ushort_t)0;
    }
    if (idx < 128 * 512) W2b[idx] = f2bf(W2[idx]);
    if (idx == 0) stats[0] = 0.0f;
}

// ---------- xconvert: x/xu fp32 -> Xb bf16 padded [69632][800] ----------
// one thread per 16-element chunk; 50 chunks/row (chunk 49 = zero pad)
__global__ __launch_bounds__(256) void xconvert_kernel(
    const float* __restrict__ x, const float* __restrict__ xu,
    ushort_t* __restrict__ Xb)
{
    int idx = blockIdx.x * 256 + threadIdx.x;   // < 69632*50 = 3481600 exact
    int r = idx / 50, c = idx - r * 50;
    uint4 lo, hi;
    if (c < 49) {
        const float* src = (r < 65536) ? (x + (size_t)r * 784)
                                       : (xu + (size_t)(r - 65536) * 784);
        const float4* p = (const float4*)(src + c * 16);
        float4 f0 = p[0], f1 = p[1], f2 = p[2], f3 = p[3];
        lo.x = ((unsigned)f2bf(f0.y) << 16) | f2bf(f0.x);
        lo.y = ((unsigned)f2bf(f0.w) << 16) | f2bf(f0.z);
        lo.z = ((unsigned)f2bf(f1.y) << 16) | f2bf(f1.x);
        lo.w = ((unsigned)f2bf(f1.w) << 16) | f2bf(f1.z);
        hi.x = ((unsigned)f2bf(f2.y) << 16) | f2bf(f2.x);
        hi.y = ((unsigned)f2bf(f2.w) << 16) | f2bf(f2.z);
        hi.z = ((unsigned)f2bf(f3.y) << 16) | f2bf(f3.x);
        hi.w = ((unsigned)f2bf(f3.w) << 16) | f2bf(f3.z);
    } else {
        lo = make_uint4(0, 0, 0, 0);
        hi = make_uint4(0, 0, 0, 0);
    }
    uint4* dst = (uint4*)(Xb + (size_t)r * 800 + c * 16);
    dst[0] = lo;
    dst[1] = hi;
}

// ---------- gemm1 (fast): h1 = relu(Xb @ W1p^T + b1), all-bf16 async ----------
// grid 2176 = 8 XCD-groups x (68 tile_m x 4 tile_n); same-tile_m blocks share XCD
__global__ __launch_bounds__(256) void gemm1_kernel(
    const ushort_t* __restrict__ Xb, const ushort_t* __restrict__ W1p,
    const float* __restrict__ b1, ushort_t* __restrict__ h1)
{
    __shared__ ushort_t As[128 * 32];
    __shared__ ushort_t Bs[128 * 32];

    const int b = blockIdx.x;
    const int xcd = b & 7, s = b >> 3;
    const int tile_n = s & 3;
    const int tile_m = xcd * 68 + (s >> 2);

    const int tid = threadIdx.x;
    const int w = tid >> 6, lane = tid & 63;
    const int wm = w >> 1, wn = w & 1;
    const int quad = lane >> 4, lc = lane & 15;
    const int row_in = lane >> 2;
    const int koff = (lane & 3) * 8;

    f32x4 acc[4][4];
#pragma unroll
    for (int i = 0; i < 4; i++)
#pragma unroll
        for (int j = 0; j < 4; j++)
#pragma unroll
            for (int r = 0; r < 4; r++) acc[i][j][r] = 0.0f;

    for (int k0 = 0; k0 < 800; k0 += 32) {
#pragma unroll
        for (int c = 0; c < 2; c++) {
            int row = (w * 2 + c) * 16 + row_in;
            const ushort_t* srcA =
                Xb + (size_t)(tile_m * 128 + row) * 800 + k0 + koff;
            GLDS16(srcA, As + (w * 2 + c) * 512);
            const ushort_t* srcB =
                W1p + (size_t)(tile_n * 128 + row) * 800 + k0 + koff;
            GLDS16(srcB, Bs + (w * 2 + c) * 512);
        }
        __syncthreads();

        bf16x8 af[4], bfr[4];
#pragma unroll
        for (int i = 0; i < 4; i++)
            af[i] = *(const bf16x8*)&As[(wm * 64 + i * 16 + lc) * 32 + quad * 8];
#pragma unroll
        for (int j = 0; j < 4; j++)
            bfr[j] = *(const bf16x8*)&Bs[(wn * 64 + j * 16 + lc) * 32 + quad * 8];
#pragma unroll
        for (int i = 0; i < 4; i++)
#pragma unroll
            for (int j = 0; j < 4; j++)
                acc[i][j] = __builtin_amdgcn_mfma_f32_16x16x32_bf16(
                    af[i], bfr[j], acc[i][j], 0, 0, 0);
        __syncthreads();
    }

    float bias[4];
#pragma unroll
    for (int j = 0; j < 4; j++)
        bias[j] = b1[tile_n * 128 + wn * 64 + j * 16 + lc];
#pragma unroll
    for (int i = 0; i < 4; i++) {
        int gr0 = tile_m * 128 + wm * 64 + i * 16 + quad * 4;
#pragma unroll
        for (int j = 0; j < 4; j++) {
            int gc = tile_n * 128 + wn * 64 + j * 16 + lc;
#pragma unroll
            for (int r = 0; r < 4; r++) {
                float v = acc[i][j][r] + bias[j];
                v = fmaxf(v, 0.0f);
                h1[(size_t)(gr0 + r) * 512 + gc] = f2bf(v);
            }
        }
    }
}

// ---------- gemm1 (fallback, round-1 proven): inline fp32->bf16 staging ----------
__global__ __launch_bounds__(256) void gemm1_inline_kernel(
    const float* __restrict__ x, const float* __restrict__ xu,
    const ushort_t* __restrict__ W1p, const float* __restrict__ b1,
    ushort_t* __restrict__ h1)
{
    __shared__ ushort_t As[128 * 32];
    __shared__ ushort_t Bs[128 * 32];

    const int tile_n = blockIdx.x & 3;
    const int tile_m = blockIdx.x >> 2;
    const int tid = threadIdx.x;
    const int w = tid >> 6, lane = tid & 63;
    const int wm = w >> 1, wn = w & 1;
    const int quad = lane >> 4, lc = lane & 15;

    const int arow = tid >> 1;
    const int akoff = (tid & 1) * 16;
    const int grow = tile_m * 128 + arow;
    const float* asrc = (grow < 65536) ? (x + (size_t)grow * 784)
                                       : (xu + (size_t)(grow - 65536) * 784);
    const int brow_in = (lane >> 2);
    const int bkoff = (lane & 3) * 8;

    f32x4 acc[4][4];
#pragma unroll
    for (int i = 0; i < 4; i++)
#pragma unroll
        for (int j = 0; j < 4; j++)
#pragma unroll
            for (int r = 0; r < 4; r++) acc[i][j][r] = 0.0f;

    for (int k0 = 0; k0 < 800; k0 += 32) {
#pragma unroll
        for (int c = 0; c < 2; c++) {
            int row = (w * 2 + c) * 16 + brow_in;
            const ushort_t* src =
                W1p + (size_t)(tile_n * 128 + row) * 800 + k0 + bkoff;
            GLDS16(src, Bs + (w * 2 + c) * 512);
        }
        {
            int kch = k0 + akoff;
            uint4 lo, hi;
            if (kch < 784) {
                const float4* p = (const float4*)(asrc + kch);
                float4 f0 = p[0], f1 = p[1], f2 = p[2], f3 = p[3];
                lo.x = ((unsigned)f2bf(f0.y) << 16) | f2bf(f0.x);
                lo.y = ((unsigned)f2bf(f0.w) << 16) | f2bf(f0.z);
                lo.z = ((unsigned)f2bf(f1.y) << 16) | f2bf(f1.x);
                lo.w = ((unsigned)f2bf(f1.w) << 16) | f2bf(f1.z);
                hi.x = ((unsigned)f2bf(f2.y) << 16) | f2bf(f2.x);
                hi.y = ((unsigned)f2bf(f2.w) << 16) | f2bf(f2.z);
                hi.z = ((unsigned)f2bf(f3.y) << 16) | f2bf(f3.x);
                hi.w = ((unsigned)f2bf(f3.w) << 16) | f2bf(f3.z);
            } else {
                lo = make_uint4(0, 0, 0, 0);
                hi = make_uint4(0, 0, 0, 0);
            }
            *(uint4*)&As[arow * 32 + akoff] = lo;
            *(uint4*)&As[arow * 32 + akoff + 8] = hi;
        }
        __syncthreads();

        bf16x8 af[4], bfr[4];
#pragma unroll
        for (int i = 0; i < 4; i++)
            af[i] = *(const bf16x8*)&As[(wm * 64 + i * 16 + lc) * 32 + quad * 8];
#pragma unroll
        for (int j = 0; j < 4; j++)
            bfr[j] = *(const bf16x8*)&Bs[(wn * 64 + j * 16 + lc) * 32 + quad * 8];
#pragma unroll
        for (int i = 0; i < 4; i++)
#pragma unroll
            for (int j = 0; j < 4; j++)
                acc[i][j] = __builtin_amdgcn_mfma_f32_16x16x32_bf16(
                    af[i], bfr[j], acc[i][j], 0, 0, 0);
        __syncthreads();
    }

    float bias[4];
#pragma unroll
    for (int j = 0; j < 4; j++)
        bias[j] = b1[tile_n * 128 + wn * 64 + j * 16 + lc];
#pragma unroll
    for (int i = 0; i < 4; i++) {
        int gr0 = tile_m * 128 + wm * 64 + i * 16 + quad * 4;
#pragma unroll
        for (int j = 0; j < 4; j++) {
            int gc = tile_n * 128 + wn * 64 + j * 16 + lc;
#pragma unroll
            for (int r = 0; r < 4; r++) {
                float v = acc[i][j][r] + bias[j];
                v = fmaxf(v, 0.0f);
                h1[(size_t)(gr0 + r) * 512 + gc] = f2bf(v);
            }
        }
    }
}

// ---------- gemm2: h2 = relu(h1 @ W2b^T + b2); 64x128 tiles, grid 1088 ----------
__global__ __launch_bounds__(256) void gemm2_kernel(
    const ushort_t* __restrict__ h1, const ushort_t* __restrict__ W2b,
    const float* __restrict__ b2, ushort_t* __restrict__ h2)
{
    __shared__ ushort_t As[64 * 32];
    __shared__ ushort_t Bs[128 * 32];

    const int tile_m = blockIdx.x;
    const int tid = threadIdx.x;
    const int w = tid >> 6, lane = tid & 63;
    const int wm = w >> 1, wn = w & 1;
    const int quad = lane >> 4, lc = lane & 15;
    const int row_in = lane >> 2;
    const int koff = (lane & 3) * 8;

    f32x4 acc[2][4];
#pragma unroll
    for (int i = 0; i < 2; i++)
#pragma unroll
        for (int j = 0; j < 4; j++)
#pragma unroll
            for (int r = 0; r < 4; r++) acc[i][j][r] = 0.0f;

    for (int k0 = 0; k0 < 512; k0 += 32) {
        {
            int row = w * 16 + row_in;
            const ushort_t* srcA =
                h1 + (size_t)(tile_m * 64 + row) * 512 + k0 + koff;
            GLDS16(srcA, As + w * 512);
        }
#pragma unroll
        for (int c = 0; c < 2; c++) {
            int row = (w * 2 + c) * 16 + row_in;
            const ushort_t* srcB = W2b + (size_t)row * 512 + k0 + koff;
            GLDS16(srcB, Bs + (w * 2 + c) * 512);
        }
        __syncthreads();

        bf16x8 af[2], bfr[4];
#pragma unroll
        for (int i = 0; i < 2; i++)
            af[i] = *(const bf16x8*)&As[(wm * 32 + i * 16 + lc) * 32 + quad * 8];
#pragma unroll
        for (int j = 0; j < 4; j++)
            bfr[j] = *(const bf16x8*)&Bs[(wn * 64 + j * 16 + lc) * 32 + quad * 8];
#pragma unroll
        for (int i = 0; i < 2; i++)
#pragma unroll
            for (int j = 0; j < 4; j++)
                acc[i][j] = __builtin_amdgcn_mfma_f32_16x16x32_bf16(
                    af[i], bfr[j], acc[i][j], 0, 0, 0);
        __syncthreads();
    }

    float bias[4];
#pragma unroll
    for (int j = 0; j < 4; j++) bias[j] = b2[wn * 64 + j * 16 + lc];
#pragma unroll
    for (int i = 0; i < 2; i++) {
        int gr0 = tile_m * 64 + wm * 32 + i * 16 + quad * 4;
#pragma unroll
        for (int j = 0; j < 4; j++) {
            int gc = wn * 64 + j * 16 + lc;
#pragma unroll
            for (int r = 0; r < 4; r++) {
                float v = acc[i][j][r] + bias[j];
                v = fmaxf(v, 0.0f);
                h2[(size_t)(gr0 + r) * 128 + gc] = f2bf(v);
            }
        }
    }
}

// ---------- fused fc3 + BCE partial / unlabeled logits ----------
__global__ __launch_bounds__(256) void loss_kernel(
    const ushort_t* __restrict__ h2, const int* __restrict__ y,
    const float* __restrict__ W3, const float* __restrict__ b3,
    float* __restrict__ stats, float* __restrict__ logits_u)
{
    __shared__ float W3s[10 * 128];
    __shared__ float b3s[10];
    __shared__ ushort_t h2s[64 * 128];
    __shared__ float red[4];

    const int tid = threadIdx.x;
    for (int i = tid; i < 1280; i += 256) W3s[i] = W3[i];
    if (tid < 10) b3s[tid] = b3[tid];

    const size_t row0 = (size_t)blockIdx.x * 64;
    const ushort_t* src = h2 + row0 * 128;
#pragma unroll
    for (int i = tid * 8; i < 64 * 128; i += 256 * 8)
        *(uint4*)&h2s[i] = *(const uint4*)&src[i];
    __syncthreads();

    float bce_part = 0.0f;
    for (int o = tid; o < 640; o += 256) {
        int r = o / 10, c = o - r * 10;
        size_t grow = row0 + r;
        float acc = b3s[c];
        const ushort_t* hr = &h2s[r * 128];
        const float* wr = &W3s[c * 128];
#pragma unroll 8
        for (int k = 0; k < 128; k++) acc += bf2f(hr[k]) * wr[k];
        if (grow < 65536) {
            float t = (y[grow] == c) ? 1.0f : 0.0f;
            bce_part += fmaxf(acc, 0.0f) - acc * t +
                        log1pf(__expf(-fabsf(acc)));
        } else {
            logits_u[(grow - 65536) * 10 + c] = acc;
        }
    }
#pragma unroll
    for (int s = 32; s > 0; s >>= 1) bce_part += __shfl_down(bce_part, s, 64);
    if ((tid & 63) == 0) red[tid >> 6] = bce_part;
    __syncthreads();
    if (tid == 0) {
        float v = red[0] + red[1] + red[2] + red[3];
        atomicAdd(stats, v);
    }
}

// ---------- semantic-loss finisher: 640 threads, all lanes active ----------
// log_s[c] = S[c] + logsumexp_i(o_i[c]),  S[c] = sum_i logsigmoid(-o_i[c])
__global__ __launch_bounds__(640) void finisher_kernel(
    const float* __restrict__ logits_u, const float* __restrict__ stats,
    float* __restrict__ out)
{
    __shared__ float Rs[64][10];
    __shared__ float Rm[64][10];
    __shared__ float Scol[10], Mcol[10];

    const int tid = threadIdx.x;
    const int g = tid / 10, c = tid - g * 10;   // 64 groups x 10 cols
    float s = 0.0f, m = -1e30f;
    for (int i = g; i < 4096; i += 64) {
        float o = logits_u[i * 10 + c];
        s += fminf(-o, 0.0f) - log1pf(__expf(-fabsf(o)));
        m = fmaxf(m, o);
    }
    Rs[g][c] = s;
    Rm[g][c] = m;
    __syncthreads();
    if (tid < 10) {
        float ss = 0.0f, mm = -1e30f;
        for (int gg = 0; gg < 64; gg++) {
            ss += Rs[gg][tid];
            mm = fmaxf(mm, Rm[gg][tid]);
        }
        Scol[tid] = ss;
        Mcol[tid] = mm;
    }
    __syncthreads();
    float e = 0.0f;
    float mm = Mcol[c];
    for (int i = g; i < 4096; i += 64)
        e += __expf(logits_u[i * 10 + c] - mm);
    Rs[g][c] = e;
    __syncthreads();
    if (tid == 0) {
        float sl = 0.0f;
        for (int cc = 0; cc < 10; cc++) {
            float ee = 0.0f;
            for (int gg = 0; gg < 64; gg++) ee += Rs[gg][cc];
            sl += -(Scol[cc] + Mcol[cc] + __logf(ee));
        }
        sl *= 0.1f;
        out[0] = stats[0] * (1.0f / (65536.0f * 10.0f));
        out[1] = sl;
    }
}

// ---------- launch ----------
extern "C" void kernel_launch(void* const* d_in, const int* in_sizes, int n_in,
                              void* d_out, int out_size, void* d_ws,
                              size_t ws_size, hipStream_t stream)
{
    const float* x  = (const float*)d_in[0];   // 65536x784
    const int*   y  = (const int*)d_in[1];     // 65536
    const float* xu = (const float*)d_in[2];   // 4096x784
    const float* W1 = (const float*)d_in[3];   // 512x784
    const float* b1 = (const float*)d_in[4];   // 512
    const float* W2 = (const float*)d_in[5];   // 128x512
    const float* b2 = (const float*)d_in[6];   // 128
    const float* W3 = (const float*)d_in[7];   // 10x128
    const float* b3 = (const float*)d_in[8];   // 10
    float* out = (float*)d_out;

    char* ws = (char*)d_ws;
    // layout (bytes):
    ushort_t* W1p      = (ushort_t*)(ws + 0);          // 819200
    ushort_t* W2b      = (ushort_t*)(ws + 819200);     // 131072 -> 950272
    float*    stats    = (float*)(ws + 950272);        // 256    -> 950528
    float*    logits_u = (float*)(ws + 950528);        // 163840 -> 1114368
    ushort_t* h1       = (ushort_t*)(ws + 1114368);    // 71303168 -> 72417536
    ushort_t* h2       = (ushort_t*)(ws + 72417536);   // 17825792 (aliases Xb region start; Xb dead after gemm1)
    ushort_t* Xb       = (ushort_t*)(ws + 72417536);   // 111411200 -> 183828736
    const size_t FAST_WS_NEED = 183828736;

    prep_kernel<<<1600, 256, 0, stream>>>(W1, W2, W1p, W2b, stats);
    if (ws_size >= FAST_WS_NEED) {
        // fast path: pre-converted bf16 X, all-async GEMM1, XCD-grouped tiles
        xconvert_kernel<<<13600, 256, 0, stream>>>(x, xu, Xb);
        gemm1_kernel<<<2176, 256, 0, stream>>>(Xb, W1p, b1, h1);
    } else {
        gemm1_inline_kernel<<<2176, 256, 0, stream>>>(x, xu, W1p, b1, h1);
    }
    gemm2_kernel<<<1088, 256, 0, stream>>>(h1, W2b, b2, h2);
    loss_kernel<<<1088, 256, 0, stream>>>(h2, y, W3, b3, stats, logits_u);
    finisher_kernel<<<1, 640, 0, stream>>>(logits_u, stats, out);
    (void)in_sizes; (void)n_in; (void)out_size; (void)ws_size;
}

// Round 3
// 503.307 us; speedup vs baseline: 1.1380x; 1.0985x over previous
//
#include <hip/hip_runtime.h>
#include <hip/hip_bf16.h>
#include <stdint.h>

typedef unsigned short ushort_t;
typedef __bf16 bf16x8 __attribute__((ext_vector_type(8)));
typedef float f32x4 __attribute__((ext_vector_type(4)));

// ---------- helpers ----------
__device__ __forceinline__ ushort_t f2bf(float f) {
    union { float f; unsigned u; } v; v.f = f;
    unsigned u = v.u;
    unsigned r = u + 0x7fffu + ((u >> 16) & 1u);   // RNE
    return (ushort_t)(r >> 16);
}
__device__ __forceinline__ float bf2f(ushort_t h) {
    union { unsigned u; float f; } v; v.u = ((unsigned)h) << 16;
    return v.f;
}

#define GLDS16(gsrc, ldst)                                                    \
    __builtin_amdgcn_global_load_lds(                                         \
        (const __attribute__((address_space(1))) void*)(gsrc),                \
        (__attribute__((address_space(3))) void*)(ldst), 16, 0, 0)

// ---------- prep: W1 -> padded bf16 [512][800], W2 -> bf16, stats=0 ----------
__global__ __launch_bounds__(256) void prep_kernel(
    const float* __restrict__ W1, const float* __restrict__ W2,
    ushort_t* __restrict__ W1p, ushort_t* __restrict__ W2b,
    float* __restrict__ stats)
{
    int idx = blockIdx.x * 256 + threadIdx.x;
    if (idx < 512 * 800) {
        int n = idx / 800, k = idx - n * 800;
        W1p[idx] = (k < 784) ? f2bf(W1[n * 784 + k]) : (ushort_t)0;
    }
    if (idx < 128 * 512) W2b[idx] = f2bf(W2[idx]);
    if (idx == 0) stats[0] = 0.0f;
}

// ---------- gemm1f: h1 = relu(X @ W1p^T + b1) ----------
// 128x128 tile, dual 32-wide K panels per barrier pair (13 sync rounds).
// A (fp32 x) is register-prefetched one iteration ahead and converted to
// bf16 during the staging phase (no load-latency serialization before the
// barrier); B comes via async global_load_lds (16B).
// grid 2176 = 8 XCDs x 68 tile_m x 4 tile_n; same-tile_m blocks share an XCD
// so the fp32 A rows are fetched from HBM once per XCD.
__global__ __launch_bounds__(256) void gemm1f_kernel(
    const float* __restrict__ x, const float* __restrict__ xu,
    const ushort_t* __restrict__ W1p, const float* __restrict__ b1,
    ushort_t* __restrict__ h1)
{
    __shared__ ushort_t As[2][128 * 32];   // 16 KB
    __shared__ ushort_t Bs[2][128 * 32];   // 16 KB

    const int b = blockIdx.x;
    const int xcd = b & 7, s = b >> 3;
    const int tile_n = s & 3;
    const int tile_m = xcd * 68 + (s >> 2);

    const int tid = threadIdx.x;
    const int w = tid >> 6, lane = tid & 63;
    const int wm = w >> 1, wn = w & 1;
    const int quad = lane >> 4, lc = lane & 15;
    const int row_in = lane >> 2;
    const int koff = (lane & 3) * 8;

    // A convert-staging geometry: 2 threads/row, 16 floats each
    const int arow = tid >> 1;
    const int akoff = (tid & 1) * 16;
    const int grow = tile_m * 128 + arow;
    const float* asrc = (grow < 65536) ? (x + (size_t)grow * 784)
                                       : (xu + (size_t)(grow - 65536) * 784);
    ushort_t* adst0 = &As[0][arow * 32 + akoff];
    ushort_t* adst1 = &As[1][arow * 32 + akoff];

    f32x4 acc[4][4];
#pragma unroll
    for (int i = 0; i < 4; i++)
#pragma unroll
        for (int j = 0; j < 4; j++)
#pragma unroll
            for (int r = 0; r < 4; r++) acc[i][j][r] = 0.0f;

    // preload first two A chunks (k = akoff, 32+akoff; always valid)
    float4 p0a, p0b, p0c, p0d, p1a, p1b, p1c, p1d;
    {
        const float4* q0 = (const float4*)(asrc + akoff);
        p0a = q0[0]; p0b = q0[1]; p0c = q0[2]; p0d = q0[3];
        const float4* q1 = (const float4*)(asrc + 32 + akoff);
        p1a = q1[0]; p1b = q1[1]; p1c = q1[2]; p1d = q1[3];
    }

    for (int k0 = 0; k0 < 800; k0 += 64) {
        const bool has2 = (k0 + 32) < 800;   // false only at k0 = 768

        // ---- async B staging (both panels) ----
#pragma unroll
        for (int c = 0; c < 2; c++) {
            int row = (w * 2 + c) * 16 + row_in;
            const ushort_t* srcB =
                W1p + (size_t)(tile_n * 128 + row) * 800 + k0 + koff;
            GLDS16(srcB, &Bs[0][(w * 2 + c) * 512]);
        }
        if (has2) {
#pragma unroll
            for (int c = 0; c < 2; c++) {
                int row = (w * 2 + c) * 16 + row_in;
                const ushort_t* srcB =
                    W1p + (size_t)(tile_n * 128 + row) * 800 + k0 + 32 + koff;
                GLDS16(srcB, &Bs[1][(w * 2 + c) * 512]);
            }
        }

        // ---- A staging from prefetched regs ----
        {
            uint4 lo, hi;
            if (k0 + akoff <= 768) {   // chunk fully valid
                lo.x = ((unsigned)f2bf(p0a.y) << 16) | f2bf(p0a.x);
                lo.y = ((unsigned)f2bf(p0a.w) << 16) | f2bf(p0a.z);
                lo.z = ((unsigned)f2bf(p0b.y) << 16) | f2bf(p0b.x);
                lo.w = ((unsigned)f2bf(p0b.w) << 16) | f2bf(p0b.z);
                hi.x = ((unsigned)f2bf(p0c.y) << 16) | f2bf(p0c.x);
                hi.y = ((unsigned)f2bf(p0c.w) << 16) | f2bf(p0c.z);
                hi.z = ((unsigned)f2bf(p0d.y) << 16) | f2bf(p0d.x);
                hi.w = ((unsigned)f2bf(p0d.w) << 16) | f2bf(p0d.z);
            } else {
                lo = make_uint4(0, 0, 0, 0);
                hi = make_uint4(0, 0, 0, 0);
            }
            *(uint4*)adst0 = lo;
            *(uint4*)(adst0 + 8) = hi;
        }
        if (has2) {
            uint4 lo, hi;
            if (k0 + 32 + akoff <= 768) {
                lo.x = ((unsigned)f2bf(p1a.y) << 16) | f2bf(p1a.x);
                lo.y = ((unsigned)f2bf(p1a.w) << 16) | f2bf(p1a.z);
                lo.z = ((unsigned)f2bf(p1b.y) << 16) | f2bf(p1b.x);
                lo.w = ((unsigned)f2bf(p1b.w) << 16) | f2bf(p1b.z);
                hi.x = ((unsigned)f2bf(p1c.y) << 16) | f2bf(p1c.x);
                hi.y = ((unsigned)f2bf(p1c.w) << 16) | f2bf(p1c.z);
                hi.z = ((unsigned)f2bf(p1d.y) << 16) | f2bf(p1d.x);
                hi.w = ((unsigned)f2bf(p1d.w) << 16) | f2bf(p1d.z);
            } else {
                lo = make_uint4(0, 0, 0, 0);
                hi = make_uint4(0, 0, 0, 0);
            }
            *(uint4*)adst1 = lo;
            *(uint4*)(adst1 + 8) = hi;
        }

        // ---- prefetch next iteration's A chunks (overlaps barrier drain) ----
        {
            int kn0 = k0 + 64 + akoff;
            if (kn0 <= 768) {
                const float4* q = (const float4*)(asrc + kn0);
                p0a = q[0]; p0b = q[1]; p0c = q[2]; p0d = q[3];
            }
            int kn1 = k0 + 96 + akoff;
            if (kn1 <= 768) {
                const float4* q = (const float4*)(asrc + kn1);
                p1a = q[0]; p1b = q[1]; p1c = q[2]; p1d = q[3];
            }
        }
        __syncthreads();

        // ---- compute: panel 0 (+ panel 1) ----
        {
            bf16x8 af[4], bfr[4];
#pragma unroll
            for (int i = 0; i < 4; i++)
                af[i] = *(const bf16x8*)&As[0][(wm * 64 + i * 16 + lc) * 32 + quad * 8];
#pragma unroll
            for (int j = 0; j < 4; j++)
                bfr[j] = *(const bf16x8*)&Bs[0][(wn * 64 + j * 16 + lc) * 32 + quad * 8];
#pragma unroll
            for (int i = 0; i < 4; i++)
#pragma unroll
                for (int j = 0; j < 4; j++)
                    acc[i][j] = __builtin_amdgcn_mfma_f32_16x16x32_bf16(
                        af[i], bfr[j], acc[i][j], 0, 0, 0);
        }
        if (has2) {
            bf16x8 af[4], bfr[4];
#pragma unroll
            for (int i = 0; i < 4; i++)
                af[i] = *(const bf16x8*)&As[1][(wm * 64 + i * 16 + lc) * 32 + quad * 8];
#pragma unroll
            for (int j = 0; j < 4; j++)
                bfr[j] = *(const bf16x8*)&Bs[1][(wn * 64 + j * 16 + lc) * 32 + quad * 8];
#pragma unroll
            for (int i = 0; i < 4; i++)
#pragma unroll
                for (int j = 0; j < 4; j++)
                    acc[i][j] = __builtin_amdgcn_mfma_f32_16x16x32_bf16(
                        af[i], bfr[j], acc[i][j], 0, 0, 0);
        }
        __syncthreads();
    }

    // epilogue: relu(acc + b1) -> bf16
    float bias[4];
#pragma unroll
    for (int j = 0; j < 4; j++)
        bias[j] = b1[tile_n * 128 + wn * 64 + j * 16 + lc];
#pragma unroll
    for (int i = 0; i < 4; i++) {
        int gr0 = tile_m * 128 + wm * 64 + i * 16 + quad * 4;
#pragma unroll
        for (int j = 0; j < 4; j++) {
            int gc = tile_n * 128 + wn * 64 + j * 16 + lc;
#pragma unroll
            for (int r = 0; r < 4; r++) {
                float v = acc[i][j][r] + bias[j];
                v = fmaxf(v, 0.0f);
                h1[(size_t)(gr0 + r) * 512 + gc] = f2bf(v);
            }
        }
    }
}

// ---------- gemm23: h2 = relu(h1 @ W2b^T + b2) fused with fc3 + losses ----------
// 64x128 tile (full N), K=512 in 8 dual-panel rounds; h2 never leaves LDS.
// Labeled rows -> BCE partial (atomicAdd); unlabeled rows -> logits_u.
__global__ __launch_bounds__(256) void gemm23_kernel(
    const ushort_t* __restrict__ h1, const ushort_t* __restrict__ W2b,
    const float* __restrict__ b2, const int* __restrict__ y,
    const float* __restrict__ W3, const float* __restrict__ b3,
    float* __restrict__ stats, float* __restrict__ logits_u)
{
    __shared__ ushort_t As[2][64 * 32];    // 8 KB
    __shared__ ushort_t Bs[2][128 * 32];   // 16 KB (reused as h2 tile later)
    __shared__ float W3s[1280];
    __shared__ float b3s[10];
    __shared__ float red[4];

    const int tid = threadIdx.x;
    const int w = tid >> 6, lane = tid & 63;
    const int wm = w >> 1, wn = w & 1;
    const int quad = lane >> 4, lc = lane & 15;
    const int row_in = lane >> 2;
    const int koff = (lane & 3) * 8;
    const int tile_m = blockIdx.x;

    for (int i = tid; i < 1280; i += 256) W3s[i] = W3[i];
    if (tid < 10) b3s[tid] = b3[tid];

    f32x4 acc[2][4];
#pragma unroll
    for (int i = 0; i < 2; i++)
#pragma unroll
        for (int j = 0; j < 4; j++)
#pragma unroll
            for (int r = 0; r < 4; r++) acc[i][j][r] = 0.0f;

    for (int k0 = 0; k0 < 512; k0 += 64) {
#pragma unroll
        for (int p = 0; p < 2; p++) {
            {   // A: 4 KB/panel, one 1KB chunk per wave
                int rowA = w * 16 + row_in;
                const ushort_t* srcA =
                    h1 + (size_t)(tile_m * 64 + rowA) * 512 + k0 + p * 32 + koff;
                GLDS16(srcA, &As[p][w * 512]);
            }
#pragma unroll
            for (int c = 0; c < 2; c++) {   // B: 8 KB/panel, 2 chunks per wave
                int rowB = (w * 2 + c) * 16 + row_in;
                const ushort_t* srcB =
                    W2b + (size_t)rowB * 512 + k0 + p * 32 + koff;
                GLDS16(srcB, &Bs[p][(w * 2 + c) * 512]);
            }
        }
        __syncthreads();
#pragma unroll
        for (int p = 0; p < 2; p++) {
            bf16x8 af[2], bfr[4];
#pragma unroll
            for (int i = 0; i < 2; i++)
                af[i] = *(const bf16x8*)&As[p][(wm * 32 + i * 16 + lc) * 32 + quad * 8];
#pragma unroll
            for (int j = 0; j < 4; j++)
                bfr[j] = *(const bf16x8*)&Bs[p][(wn * 64 + j * 16 + lc) * 32 + quad * 8];
#pragma unroll
            for (int i = 0; i < 2; i++)
#pragma unroll
                for (int j = 0; j < 4; j++)
                    acc[i][j] = __builtin_amdgcn_mfma_f32_16x16x32_bf16(
                        af[i], bfr[j], acc[i][j], 0, 0, 0);
        }
        __syncthreads();
    }

    // stage h2 tile (bias+relu, bf16) into LDS over Bs (done reading it)
    ushort_t* h2s = &Bs[0][0];   // 64*128 ushort = 16 KB
    float bias[4];
#pragma unroll
    for (int j = 0; j < 4; j++) bias[j] = b2[wn * 64 + j * 16 + lc];
#pragma unroll
    for (int i = 0; i < 2; i++) {
        int row0 = wm * 32 + i * 16 + quad * 4;
#pragma unroll
        for (int j = 0; j < 4; j++) {
            int col = wn * 64 + j * 16 + lc;
#pragma unroll
            for (int r = 0; r < 4; r++) {
                float v = fmaxf(acc[i][j][r] + bias[j], 0.0f);
                h2s[(row0 + r) * 128 + col] = f2bf(v);
            }
        }
    }
    __syncthreads();

    // fc3 + loss
    const size_t row0g = (size_t)tile_m * 64;
    float bce_part = 0.0f;
    for (int o = tid; o < 640; o += 256) {
        int r = o / 10, c = o - r * 10;
        size_t grw = row0g + r;
        float a = b3s[c];
        const ushort_t* hr = &h2s[r * 128];
        const float* wr = &W3s[c * 128];
#pragma unroll 8
        for (int k = 0; k < 128; k++) a += bf2f(hr[k]) * wr[k];
        if (grw < 65536) {
            float t = (y[grw] == c) ? 1.0f : 0.0f;
            bce_part += fmaxf(a, 0.0f) - a * t + log1pf(__expf(-fabsf(a)));
        } else {
            logits_u[(grw - 65536) * 10 + c] = a;
        }
    }
#pragma unroll
    for (int s = 32; s > 0; s >>= 1) bce_part += __shfl_down(bce_part, s, 64);
    if ((tid & 63) == 0) red[tid >> 6] = bce_part;
    __syncthreads();
    if (tid == 0) atomicAdd(stats, red[0] + red[1] + red[2] + red[3]);
}

// ---------- finisher: semantic loss + output write ----------
// log_s[c] = S[c] + logsumexp_i(o_i[c]),  S[c] = sum_i logsigmoid(-o_i[c])
__global__ __launch_bounds__(640) void finisher_kernel(
    const float* __restrict__ logits_u, const float* __restrict__ stats,
    float* __restrict__ out)
{
    __shared__ float Rs[64][10];
    __shared__ float Rm[64][10];
    __shared__ float Scol[10], Mcol[10];

    const int tid = threadIdx.x;
    const int g = tid / 10, c = tid - g * 10;   // 64 groups x 10 cols
    float s = 0.0f, m = -1e30f;
    for (int i = g; i < 4096; i += 64) {
        float o = logits_u[i * 10 + c];
        s += fminf(-o, 0.0f) - log1pf(__expf(-fabsf(o)));
        m = fmaxf(m, o);
    }
    Rs[g][c] = s;
    Rm[g][c] = m;
    __syncthreads();
    if (tid < 10) {
        float ss = 0.0f, mm = -1e30f;
        for (int gg = 0; gg < 64; gg++) {
            ss += Rs[gg][tid];
            mm = fmaxf(mm, Rm[gg][tid]);
        }
        Scol[tid] = ss;
        Mcol[tid] = mm;
    }
    __syncthreads();
    float e = 0.0f;
    float mm = Mcol[c];
    for (int i = g; i < 4096; i += 64)
        e += __expf(logits_u[i * 10 + c] - mm);
    Rs[g][c] = e;
    __syncthreads();
    if (tid == 0) {
        float sl = 0.0f;
        for (int cc = 0; cc < 10; cc++) {
            float ee = 0.0f;
            for (int gg = 0; gg < 64; gg++) ee += Rs[gg][cc];
            sl += -(Scol[cc] + Mcol[cc] + __logf(ee));
        }
        sl *= 0.1f;
        out[0] = stats[0] * (1.0f / (65536.0f * 10.0f));
        out[1] = sl;
    }
}

// ---------- launch ----------
extern "C" void kernel_launch(void* const* d_in, const int* in_sizes, int n_in,
                              void* d_out, int out_size, void* d_ws,
                              size_t ws_size, hipStream_t stream)
{
    const float* x  = (const float*)d_in[0];   // 65536x784
    const int*   y  = (const int*)d_in[1];     // 65536
    const float* xu = (const float*)d_in[2];   // 4096x784
    const float* W1 = (const float*)d_in[3];   // 512x784
    const float* b1 = (const float*)d_in[4];   // 512
    const float* W2 = (const float*)d_in[5];   // 128x512
    const float* b2 = (const float*)d_in[6];   // 128
    const float* W3 = (const float*)d_in[7];   // 10x128
    const float* b3 = (const float*)d_in[8];   // 10
    float* out = (float*)d_out;

    char* ws = (char*)d_ws;
    // layout (bytes), total 72.4 MB:
    ushort_t* W1p      = (ushort_t*)(ws + 0);          // 819200
    ushort_t* W2b      = (ushort_t*)(ws + 819200);     // 131072 -> 950272
    float*    stats    = (float*)(ws + 950272);        // 256    -> 950528
    float*    logits_u = (float*)(ws + 950528);        // 163840 -> 1114368
    ushort_t* h1       = (ushort_t*)(ws + 1114368);    // 71303168 -> 72417536

    prep_kernel<<<1600, 256, 0, stream>>>(W1, W2, W1p, W2b, stats);
    gemm1f_kernel<<<2176, 256, 0, stream>>>(x, xu, W1p, b1, h1);
    gemm23_kernel<<<1088, 256, 0, stream>>>(h1, W2b, b2, y, W3, b3, stats,
                                            logits_u);
    finisher_kernel<<<1, 640, 0, stream>>>(logits_u, stats, out);
    (void)in_sizes; (void)n_in; (void)out_size; (void)ws_size;
}